// Round 3
// baseline (756.735 us; speedup 1.0000x reference)
//
#include <hip/hip_runtime.h>
#include <math.h>

#define BN 4
#define HN 96
#define WN 312
#define CN 384
#define D1 49
#define HW (HN*WN)          // 29952
#define CVSZ (BN*D1*HW)     // 5,870,592 floats

// ---------------- cost volume kernel (v3) ----------------
// cost[d,h,x] = dot(featL[h,x,:], featR[h,x-d,:]) for x>=d else -inf
//
// v3: L in registers (global->VGPR, dg-duplicates hit L1), R in channel-major
// LDS read as aligned ds_read_b128.
//   thread (xg=t&15, dg=t>>4) owns x = x0+4*xg+{0..3}, d = 12*dg+{0..12}.
//   d-tiles overlap at d=12,24,36: both owners compute bitwise-identical
//   values (same inputs, same fp32 fmaf order) -> benign duplicate store.
//   R window base rb = 4*xg-12*dg+36 is a multiple of 4 -> 4x float4 LDS
//   reads, 16B-aligned (RSTRIDE=116 floats = 464 B, mult of 16).
//   Per c: 4 b128 LDS reads + 52 FMAs -> LDS pipe no longer the wall.
#define TXC 64
#define KCC 16
#define RSTRIDE 116

__global__ __launch_bounds__(64)
void k_cost(const float* __restrict__ Lf, const float* __restrict__ Rf, float* __restrict__ cv)
{
    __shared__ float Rs[KCC * RSTRIDE];   // 7424 B
    const int t = threadIdx.x;
    const int xg = t & 15;
    const int dg = t >> 4;
    const int x0 = blockIdx.x * TXC;
    const int h = blockIdx.y;
    const int b = blockIdx.z;
    const float* Lrow = Lf + (size_t)(b * HN + h) * WN * CN;
    const float* Rrow = Rf + (size_t)(b * HN + h) * WN * CN;
    const int rb = 4 * xg - 12 * dg + 36;   // in [0,96], multiple of 4
    const int d0 = 12 * dg;                 // d = d0 + j, j in [0,12]
    const int xbase = x0 + 4 * xg;

    float acc[13][4];
#pragma unroll
    for (int j = 0; j < 13; j++)
#pragma unroll
        for (int i = 0; i < 4; i++) acc[j][i] = 0.f;

    for (int c0 = 0; c0 < CN; c0 += KCC) {
        // L tile -> registers (issued before staging so latency hides)
        float Lc[4][KCC];
#pragma unroll
        for (int i = 0; i < 4; i++) {
            int gx = xbase + i;
            const float4* src = (const float4*)(Lrow + (size_t)gx * CN + c0);
#pragma unroll
            for (int g = 0; g < 4; g++) {
                float4 v = make_float4(0.f, 0.f, 0.f, 0.f);
                if (gx < WN) v = src[g];
                Lc[i][4 * g + 0] = v.x;
                Lc[i][4 * g + 1] = v.y;
                Lc[i][4 * g + 2] = v.z;
                Lc[i][4 * g + 3] = v.w;
            }
        }
        __syncthreads();
        // stage R: 112 rows x 4 quads = 448 quads -> 7 per thread (transpose)
#pragma unroll
        for (int ii = 0; ii < 7; ii++) {
            int idx = t + ii * 64;
            int row = idx >> 2, cq = idx & 3;
            int gx = x0 - 48 + row;
            float4 v = make_float4(0.f, 0.f, 0.f, 0.f);
            if (gx >= 0 && gx < WN) v = *(const float4*)(Rrow + (size_t)gx * CN + c0 + cq * 4);
            Rs[(4 * cq + 0) * RSTRIDE + row] = v.x;
            Rs[(4 * cq + 1) * RSTRIDE + row] = v.y;
            Rs[(4 * cq + 2) * RSTRIDE + row] = v.z;
            Rs[(4 * cq + 3) * RSTRIDE + row] = v.w;
        }
        __syncthreads();

#pragma unroll
        for (int c = 0; c < KCC; c++) {
            const float4* rp4 = (const float4*)&Rs[c * RSTRIDE + rb];
            float4 q0 = rp4[0], q1 = rp4[1], q2 = rp4[2], q3 = rp4[3];
            float Rv[16] = {q0.x, q0.y, q0.z, q0.w, q1.x, q1.y, q1.z, q1.w,
                            q2.x, q2.y, q2.z, q2.w, q3.x, q3.y, q3.z, q3.w};
#pragma unroll
            for (int j = 0; j < 13; j++) {
#pragma unroll
                for (int i = 0; i < 4; i++)
                    acc[j][i] = fmaf(Lc[i][c], Rv[i - j + 12], acc[j][i]);
            }
        }
    }

    const float NINF = -__builtin_inff();
#pragma unroll
    for (int j = 0; j < 13; j++) {
        int d = d0 + j;                   // always <= 48
        size_t base = ((size_t)(b * D1 + d) * HN + h) * WN;
        int x = xbase;
        float v0 = (x + 0 >= d) ? acc[j][0] : NINF;
        float v1 = (x + 1 >= d) ? acc[j][1] : NINF;
        float v2 = (x + 2 >= d) ? acc[j][2] : NINF;
        float v3 = (x + 3 >= d) ? acc[j][3] : NINF;
        if (x + 3 < WN) {
            *(float4*)(cv + base + x) = make_float4(v0, v1, v2, v3);
        } else {
            if (x + 0 < WN) cv[base + x + 0] = v0;
            if (x + 1 < WN) cv[base + x + 1] = v1;
            if (x + 2 < WN) cv[base + x + 2] = v2;
            if (x + 3 < WN) cv[base + x + 3] = v3;
        }
    }
}

// ---------------- fused post-processing ----------------
// One block per (b, h-row): ent0 -> extents -> refine1 (in LDS) -> ent1 ->
// extents -> refine2 + streaming argmax -> smooth-L1 reduce.
// All arithmetic copied verbatim (same op order) from the previously
// passing per-stage kernels. ent2 is dead in the reference; base argmax is
// dead because the loss is masked by rm2.

__device__ __forceinline__ float ent_from_lds(const float* E, int x)
{
    float v[D1];
#pragma unroll
    for (int d = 0; d < D1; d++) v[d] = E[d * WN + x];

    float m = v[0];
#pragma unroll
    for (int d = 1; d < D1; d++) m = fmaxf(m, v[d]);

    float S = 0.f;
    int cnt = 0;
#pragma unroll
    for (int d = 0; d < D1; d++) {
        if (isfinite(v[d])) cnt++;
        S += expf((v[d] - m) * 10.0f);
    }
    float lS = logf(S);
    float e_acc = 0.f;
#pragma unroll
    for (int d = 0; d < D1; d++) {
        float l = (v[d] - m) * 10.0f;
        float pe = expf(l) / S;
        if (pe > 1e-8f) e_acc -= pe * (l - lS);
        else            e_acc += 1.8420681e-7f;  // -1e-8*ln(1e-8)
    }
    float out = 0.f;
    if (cnt > 1) out = e_acc / (logf((float)cnt) + 1e-8f);
    return fminf(fmaxf(out, 0.f), 1.f);
}

// prev/next valid from a 312-bit bitmap; exact integer semantics of the
// reference cummax formulation. ROI: rows [64,95], cols [62,218].
__device__ __forceinline__ void extents_from_mask(const unsigned long long* vmask, int x,
                                                  bool valid, bool roi_row,
                                                  int* pa, int* pb, bool* prm)
{
    int prev = -1;
    int wi = x >> 6;
    unsigned long long m = vmask[wi] & (~0ULL >> (63 - (x & 63)));
    while (true) {
        if (m) { prev = (wi << 6) + 63 - __builtin_clzll(m); break; }
        if (--wi < 0) break;
        m = vmask[wi];
    }
    int nxt = WN;
    wi = x >> 6;
    m = vmask[wi] & (~0ULL << (x & 63));
    while (true) {
        if (m) { nxt = (wi << 6) + __builtin_ctzll(m); break; }
        if (++wi >= 5) break;
        m = vmask[wi];
    }
    int a = prev + 1;                       // == max(x-L,0) of the reference
    int lo = x - 12; if (lo < 0) lo = 0;
    if (a < lo) a = lo;
    int bb = (nxt > x) ? nxt - 1 : x;       // nxt==x iff valid
    if (bb > WN - 1) bb = WN - 1;
    int hi = x + 12; if (hi > WN - 1) hi = WN - 1;
    if (bb > hi) bb = hi;
    *pa = a; *pb = bb;
    *prm = (!valid) && roi_row && (x >= 62) && (x <= 218);
}

__global__ __launch_bounds__(320)
void k_post(const float* __restrict__ cv0, const float* __restrict__ st,
            float* __restrict__ accum)
{
    __shared__ float E[D1 * WN];            // 61152 B
    __shared__ unsigned long long vmask[5];
    __shared__ float r1[5], r2[5];
    const int t = threadIdx.x;
    const int h = blockIdx.x;
    const int b = blockIdx.y;
    const int x = t;
    const bool px = (x < WN);
    const bool roi_row = (h >= 64 && h <= 95);
    const float NINF = -__builtin_inff();

    // Phase A: load E0 slab
#pragma unroll 1
    for (int d = 0; d < D1; d++) {
        if (px) E[d * WN + x] = cv0[((size_t)(b * D1 + d) * HN + h) * WN + x];
    }
    __syncthreads();

    // ---- pass 1: ent0 -> extents ----
    bool valid = false;
    if (px) valid = (ent_from_lds(E, x) <= 0.6f);
    unsigned long long bal = __ballot(valid);
    if ((t & 63) == 0) vmask[t >> 6] = bal;
    __syncthreads();
    int a1, b1; bool rm1;
    extents_from_mask(vmask, x, valid, roi_row, &a1, &b1, &rm1);

    // ---- refine1: E0 -> E1 in LDS (one barrier per d-row) ----
#pragma unroll 1
    for (int d = 0; d < D1; d++) {
        float val = 0.f;
        if (rm1) {
            const float* row = &E[d * WN];
            float num = 0.f; int den = 0;
            for (int xx = a1; xx <= b1; xx++) {
                float v = row[xx];
                if (isfinite(v)) { num += v; den++; }
            }
            val = (den > 0) ? num / (float)den : NINF;
        }
        __syncthreads();                    // all reads of row d done
        if (rm1) E[d * WN + x] = val;
    }
    __syncthreads();

    // ---- pass 2: ent1 -> extents ----
    bool valid2 = false;
    if (px) valid2 = (ent_from_lds(E, x) <= 0.6f);
    unsigned long long bal2 = __ballot(valid2);
    if ((t & 63) == 0) vmask[t >> 6] = bal2;
    __syncthreads();
    int a2, b2; bool rm2;
    extents_from_mask(vmask, x, valid2, roi_row, &a2, &b2, &rm2);

    // ---- refine2 + streaming argmax + loss (rm2 pixels only, no barriers) ----
    float sl1 = 0.f, msk = 0.f;
    if (rm2) {
        float best = 0.f; int bi = 0;
#pragma unroll 1
        for (int d = 0; d < D1; d++) {
            const float* row = &E[d * WN];
            float num = 0.f; int den = 0;
            for (int xx = a2; xx <= b2; xx++) {
                float v = row[xx];
                if (isfinite(v)) { num += v; den++; }
            }
            float val = (den > 0) ? num / (float)den : NINF;
            if (d == 0 || val > best) { best = val; bi = d; }  // first-max
        }
        float diff = st[((size_t)b * HN + h) * WN + x] * 0.25f - (float)bi;
        float ad = fabsf(diff);
        sl1 = (ad < 1.f) ? 0.5f * ad * ad : ad - 0.5f;
        msk = 1.f;
    }
#pragma unroll
    for (int off = 32; off; off >>= 1) {
        sl1 += __shfl_down(sl1, off);
        msk += __shfl_down(msk, off);
    }
    if ((t & 63) == 0) { r1[t >> 6] = sl1; r2[t >> 6] = msk; }
    __syncthreads();
    if (t == 0) {
        float A = 0.f, C = 0.f;
#pragma unroll
        for (int w = 0; w < 5; w++) { A += r1[w]; C += r2[w]; }
        atomicAdd(&accum[b * 2], A);
        atomicAdd(&accum[b * 2 + 1], C);
    }
}

__global__ void k_finalize(const float* __restrict__ accum, float* __restrict__ out)
{
    if (threadIdx.x == 0 && blockIdx.x == 0) {
        float s = 0.f;
        for (int b = 0; b < BN; b++) {
            float c = accum[2 * b + 1];
            if (c < 1.f) c = 1.f;
            s += accum[2 * b] / c;
        }
        out[0] = s * 0.25f;
    }
}

extern "C" void kernel_launch(void* const* d_in, const int* in_sizes, int n_in,
                              void* d_out, int out_size, void* d_ws, size_t ws_size,
                              hipStream_t stream)
{
    const float* fL = (const float*)d_in[0];
    const float* fR = (const float*)d_in[1];
    const float* st = (const float*)d_in[2];
    float* out = (float*)d_out;

    float* cv0 = (float*)d_ws;
    float* accum = cv0 + CVSZ;

    k_cost<<<dim3(5, HN, BN), 64, 0, stream>>>(fL, fR, cv0);
    hipMemsetAsync(accum, 0, 8 * sizeof(float), stream);
    k_post<<<dim3(HN, BN), 320, 0, stream>>>(cv0, st, accum);
    k_finalize<<<1, 64, 0, stream>>>(accum, out);
}

// Round 4
// 450.773 us; speedup vs baseline: 1.6787x; 1.6787x over previous
//
#include <hip/hip_runtime.h>
#include <math.h>

#define BN 4
#define HN 96
#define WN 312
#define CN 384
#define D1 49

// Live domain (verified by rounds 0-3 passing with absmax 0.0):
// ROI rows h in [64,95], ROI cols x in [62,218]. Windows/extents reach
// x in [50,230]; cost needed only for x in [48,240), h in [64,95].
// In this domain x >= 48 >= d always -> no -inf anywhere, cnt==49.
#define HROI0 64
#define HROI 32
#define XOFF 48
#define XLEN 192          // 3 tiles of 64, covers x in [48,240)
#define CVSZ (BN*D1*HROI*XLEN)   // 1,204,224 floats (4.8 MB)

// ---------------- cost volume kernel (v4: trimmed domain + dbuf) ----------------
// cost[d,h,x] = dot(featL[h,x,:], featR[h,x-d,:])   (x>=d always here)
// 1-wave blocks, thread (xg=t&15, dg=t>>4): x = x0+4*xg+{0..3}, d = 12*dg+{0..12}
// (d-tiles overlap at 12/24/36: duplicate threads compute bitwise-identical
//  values -> benign duplicate store). R in channel-major LDS, double-buffered;
// per c: 4 aligned ds_read_b128 + 52 fmaf, c-ascending chain (bitwise same as r2/r3).
#define TXC 64
#define KCC 16
#define RSTRIDE 116
#define NT (CN/KCC)       // 24

__global__ __launch_bounds__(64)
void k_cost(const float* __restrict__ Lf, const float* __restrict__ Rf, float* __restrict__ cv)
{
    __shared__ float Rs[2][KCC * RSTRIDE];   // 2 x 7424 B
    const int t = threadIdx.x;
    const int xg = t & 15;
    const int dg = t >> 4;
    const int x0 = XOFF + blockIdx.x * TXC;     // 48,112,176
    const int hp = blockIdx.y;                  // 0..31
    const int h = HROI0 + hp;
    const int b = blockIdx.z;
    const float* Lrow = Lf + (size_t)(b * HN + h) * WN * CN;
    const float* Rrow = Rf + (size_t)(b * HN + h) * WN * CN;
    const float* Rbase = Rrow + (size_t)(x0 - 48) * CN;   // R rows [x0-48, x0+64), all in [0,240)
    const int rb = 4 * xg - 12 * dg + 36;       // mult of 4, in [0,96]
    const int d0 = 12 * dg;
    const int xbase = x0 + 4 * xg;              // in [48,236], no bounds checks needed

    const int srow[7] = { (t) >> 2, (t+64) >> 2, (t+128) >> 2, (t+192) >> 2,
                          (t+256) >> 2, (t+320) >> 2, (t+384) >> 2 };
    const int scq = t & 3;

    float acc[13][4];
#pragma unroll
    for (int j = 0; j < 13; j++)
#pragma unroll
        for (int i = 0; i < 4; i++) acc[j][i] = 0.f;

    // prologue: stage R chunk 0 into Rs[0]
    {
        float4 rq[7];
#pragma unroll
        for (int ii = 0; ii < 7; ii++)
            rq[ii] = *(const float4*)(Rbase + (size_t)srow[ii] * CN + scq * 4);
#pragma unroll
        for (int ii = 0; ii < 7; ii++) {
            Rs[0][(4 * scq + 0) * RSTRIDE + srow[ii]] = rq[ii].x;
            Rs[0][(4 * scq + 1) * RSTRIDE + srow[ii]] = rq[ii].y;
            Rs[0][(4 * scq + 2) * RSTRIDE + srow[ii]] = rq[ii].z;
            Rs[0][(4 * scq + 3) * RSTRIDE + srow[ii]] = rq[ii].w;
        }
        __syncthreads();
    }

    for (int tt = 0; tt < NT; tt++) {
        const int c0 = tt * KCC;
        const float* rsr = Rs[tt & 1];
        float* rsw = Rs[(tt + 1) & 1];
        const bool more = (tt + 1 < NT);

        // issue next R chunk's global loads (in flight across the compute phase)
        float4 rq[7];
        if (more) {
#pragma unroll
            for (int ii = 0; ii < 7; ii++)
                rq[ii] = *(const float4*)(Rbase + (size_t)srow[ii] * CN + c0 + KCC + scq * 4);
        }

        // L for this chunk -> registers (consumed in-order by compute below)
        float Lc[4][KCC];
#pragma unroll
        for (int i = 0; i < 4; i++) {
            const float4* src = (const float4*)(Lrow + (size_t)(xbase + i) * CN + c0);
#pragma unroll
            for (int g = 0; g < 4; g++) {
                float4 v = src[g];
                Lc[i][4 * g + 0] = v.x;
                Lc[i][4 * g + 1] = v.y;
                Lc[i][4 * g + 2] = v.z;
                Lc[i][4 * g + 3] = v.w;
            }
        }

#pragma unroll
        for (int c = 0; c < KCC; c++) {
            const float4* rp4 = (const float4*)&rsr[c * RSTRIDE + rb];
            float4 q0 = rp4[0], q1 = rp4[1], q2 = rp4[2], q3 = rp4[3];
            float Rv[16] = {q0.x, q0.y, q0.z, q0.w, q1.x, q1.y, q1.z, q1.w,
                            q2.x, q2.y, q2.z, q2.w, q3.x, q3.y, q3.z, q3.w};
#pragma unroll
            for (int j = 0; j < 13; j++) {
#pragma unroll
                for (int i = 0; i < 4; i++)
                    acc[j][i] = fmaf(Lc[i][c], Rv[i - j + 12], acc[j][i]);
            }
        }

        if (more) {
#pragma unroll
            for (int ii = 0; ii < 7; ii++) {
                rsw[(4 * scq + 0) * RSTRIDE + srow[ii]] = rq[ii].x;
                rsw[(4 * scq + 1) * RSTRIDE + srow[ii]] = rq[ii].y;
                rsw[(4 * scq + 2) * RSTRIDE + srow[ii]] = rq[ii].z;
                rsw[(4 * scq + 3) * RSTRIDE + srow[ii]] = rq[ii].w;
            }
        }
        __syncthreads();
    }

    // epilogue: x >= 48 >= d always -> no -inf, no guards
    const int xl = xbase - XOFF;
#pragma unroll
    for (int j = 0; j < 13; j++) {
        int d = d0 + j;     // <= 48
        size_t base = ((size_t)(b * D1 + d) * HROI + hp) * XLEN + xl;
        *(float4*)(cv + base) = make_float4(acc[j][0], acc[j][1], acc[j][2], acc[j][3]);
    }
}

// ---------------- fused post-processing (ROI rows only) ----------------
__device__ __forceinline__ float ent_from_lds(const float* E, int x)
{
    float v[D1];
#pragma unroll
    for (int d = 0; d < D1; d++) v[d] = E[d * XLEN + x];

    float m = v[0];
#pragma unroll
    for (int d = 1; d < D1; d++) m = fmaxf(m, v[d]);

    float S = 0.f;
    int cnt = 0;
#pragma unroll
    for (int d = 0; d < D1; d++) {
        if (isfinite(v[d])) cnt++;        // always true here; kept for bitwise parity
        S += expf((v[d] - m) * 10.0f);
    }
    float lS = logf(S);
    float e_acc = 0.f;
#pragma unroll
    for (int d = 0; d < D1; d++) {
        float l = (v[d] - m) * 10.0f;
        float pe = expf(l) / S;
        if (pe > 1e-8f) e_acc -= pe * (l - lS);
        else            e_acc += 1.8420681e-7f;  // -1e-8*ln(1e-8)
    }
    float out = 0.f;
    if (cnt > 1) out = e_acc / (logf((float)cnt) + 1e-8f);
    return fminf(fmaxf(out, 0.f), 1.f);
}

// extents in local coords (xl = x-48). For rm pixels the true prev/next either
// lies inside [50,230] (visible here) or is clamped away by the +/-12 window,
// so local search is exact. rm: !valid && x in [62,218] (rows already ROI).
__device__ __forceinline__ void extents3(const unsigned long long* vmask, int x,
                                         bool valid, int xglob,
                                         int* pa, int* pb, bool* prm)
{
    int prev = -1;
    int wi = x >> 6;
    unsigned long long m = vmask[wi] & (~0ULL >> (63 - (x & 63)));
    while (true) {
        if (m) { prev = (wi << 6) + 63 - __builtin_clzll(m); break; }
        if (--wi < 0) break;
        m = vmask[wi];
    }
    int nxt = XLEN;
    wi = x >> 6;
    m = vmask[wi] & (~0ULL << (x & 63));
    while (true) {
        if (m) { nxt = (wi << 6) + __builtin_ctzll(m); break; }
        if (++wi >= 3) break;
        m = vmask[wi];
    }
    int a = prev + 1;
    int lo = x - 12; if (lo < 0) lo = 0;
    if (a < lo) a = lo;
    int bb = (nxt > x) ? nxt - 1 : x;
    if (bb > XLEN - 1) bb = XLEN - 1;
    int hi = x + 12; if (hi > XLEN - 1) hi = XLEN - 1;
    if (bb > hi) bb = hi;
    *pa = a; *pb = bb;
    *prm = (!valid) && (xglob >= 62) && (xglob <= 218);
}

__global__ __launch_bounds__(192)
void k_post(const float* __restrict__ cv, const float* __restrict__ st,
            float* __restrict__ accum)
{
    __shared__ float E0[D1 * XLEN];          // 37632 B
    __shared__ float E1[D1 * XLEN];          // 37632 B
    __shared__ unsigned long long vmask[3];
    __shared__ float r1[3], r2[3];
    const int t = threadIdx.x;               // xl in [0,192)
    const int hp = blockIdx.x;               // 0..31
    const int b = blockIdx.y;
    const int xglob = XOFF + t;

    // load slab (L2-resident, coalesced)
#pragma unroll 7
    for (int d = 0; d < D1; d++)
        E0[d * XLEN + t] = cv[((size_t)(b * D1 + d) * HROI + hp) * XLEN + t];
    __syncthreads();

    // ---- pass 1: ent0 -> extents ----
    bool valid = (ent_from_lds(E0, t) <= 0.6f);
    unsigned long long bal = __ballot(valid);
    if ((t & 63) == 0) vmask[t >> 6] = bal;
    __syncthreads();
    int a1, b1; bool rm1;
    extents3(vmask, t, valid, xglob, &a1, &b1, &rm1);

    // ---- refine1: E0 -> E1, one barrier total ----
    // windows [a1,b1] subset of local [2,182]: all values finite, den = b-a+1 >= 1.
    // Fixed-25 guarded ascending adds == serial a..b loop bitwise.
#pragma unroll 1
    for (int d = 0; d < D1; d++) {
        const float* row = &E0[d * XLEN];
        float val;
        if (rm1) {
            float num = 0.f;
#pragma unroll
            for (int k = 0; k < 25; k++) {
                int xx = a1 + k;
                if (xx <= b1) num += row[xx];
            }
            val = num / (float)(b1 - a1 + 1);
        } else {
            val = row[t];
        }
        E1[d * XLEN + t] = val;
    }
    __syncthreads();

    // ---- pass 2: ent1 -> extents ----
    bool valid2 = (ent_from_lds(E1, t) <= 0.6f);
    unsigned long long bal2 = __ballot(valid2);
    if ((t & 63) == 0) vmask[t >> 6] = bal2;
    __syncthreads();
    int a2, b2; bool rm2;
    extents3(vmask, t, valid2, xglob, &a2, &b2, &rm2);

    // ---- refine2 + streaming argmax + loss (no barriers) ----
    float sl1 = 0.f, msk = 0.f;
    if (rm2) {
        float best = 0.f; int bi = 0;
#pragma unroll 1
        for (int d = 0; d < D1; d++) {
            const float* row = &E1[d * XLEN];
            float num = 0.f;
#pragma unroll
            for (int k = 0; k < 25; k++) {
                int xx = a2 + k;
                if (xx <= b2) num += row[xx];
            }
            float val = num / (float)(b2 - a2 + 1);
            if (d == 0 || val > best) { best = val; bi = d; }   // first-max
        }
        float diff = st[((size_t)(b * HN + HROI0 + hp)) * WN + xglob] * 0.25f - (float)bi;
        float ad = fabsf(diff);
        sl1 = (ad < 1.f) ? 0.5f * ad * ad : ad - 0.5f;
        msk = 1.f;
    }
#pragma unroll
    for (int off = 32; off; off >>= 1) {
        sl1 += __shfl_down(sl1, off);
        msk += __shfl_down(msk, off);
    }
    if ((t & 63) == 0) { r1[t >> 6] = sl1; r2[t >> 6] = msk; }
    __syncthreads();
    if (t == 0) {
        float A = r1[0] + r1[1] + r1[2];
        float C = r2[0] + r2[1] + r2[2];
        atomicAdd(&accum[b * 2], A);
        atomicAdd(&accum[b * 2 + 1], C);
    }
}

__global__ void k_finalize(const float* __restrict__ accum, float* __restrict__ out)
{
    if (threadIdx.x == 0 && blockIdx.x == 0) {
        float s = 0.f;
        for (int b = 0; b < BN; b++) {
            float c = accum[2 * b + 1];
            if (c < 1.f) c = 1.f;
            s += accum[2 * b] / c;
        }
        out[0] = s * 0.25f;
    }
}

extern "C" void kernel_launch(void* const* d_in, const int* in_sizes, int n_in,
                              void* d_out, int out_size, void* d_ws, size_t ws_size,
                              hipStream_t stream)
{
    const float* fL = (const float*)d_in[0];
    const float* fR = (const float*)d_in[1];
    const float* st = (const float*)d_in[2];
    float* out = (float*)d_out;

    float* cv = (float*)d_ws;
    float* accum = cv + CVSZ;

    k_cost<<<dim3(3, HROI, BN), 64, 0, stream>>>(fL, fR, cv);
    hipMemsetAsync(accum, 0, 8 * sizeof(float), stream);
    k_post<<<dim3(HROI, BN), 192, 0, stream>>>(cv, st, accum);
    k_finalize<<<1, 64, 0, stream>>>(accum, out);
}